// Round 9
// baseline (177.816 us; speedup 1.0000x reference)
//
#include <hip/hip_runtime.h>

// ---------------- problem constants ----------------
constexpr int KC    = 4096;      // NUM_EMBEDDINGS
constexpr int DIM   = 64;        // EMBEDDING_DIM
constexpr int NROWS = 73728;     // 128*24*1536/64
constexpr int NELEM = 4718592;   // 128*24*1536
constexpr int RB    = 4096;      // bytes per packed 16-code group
constexpr int RING  = 12;        // LDS ring slots

typedef _Float16 f16x8 __attribute__((ext_vector_type(8)));
typedef float    f32x4 __attribute__((ext_vector_type(4)));

// ---------------- output layout (floats) ----------------
constexpr size_t OUT_LOSS  = 0;                               // 1
constexpr size_t OUT_ZQ    = 1;                               // NELEM
constexpr size_t OUT_CODES = 1 + (size_t)NELEM;               // NROWS
constexpr size_t OUT_EMB   = OUT_CODES + (size_t)NROWS;       // KC*DIM
constexpr size_t OUT_NCS   = OUT_EMB + (size_t)KC * DIM;      // KC
constexpr size_t OUT_NEW   = OUT_NCS + (size_t)KC;            // KC*DIM

// ---------------- workspace layout (bytes) ----------------
constexpr size_t alignup(size_t x, size_t a) { return (x + a - 1) & ~(a - 1); }
constexpr size_t WS_CODES  = 0;                                            // int[NROWS]
constexpr size_t WS_COUNTS = WS_CODES + sizeof(int) * (size_t)NROWS;       // int[KC]
constexpr size_t WS_OFFS   = WS_COUNTS + sizeof(int) * (size_t)KC;         // int[KC+1]
constexpr size_t WS_CURSOR = alignup(WS_OFFS + sizeof(int) * (KC + 1), 16);// int[KC]
constexpr size_t WS_SORTED = WS_CURSOR + sizeof(int) * (size_t)KC;         // int[NROWS]
constexpr size_t WS_E2     = alignup(WS_SORTED + sizeof(int) * (size_t)NROWS, 64); // float[KC] (16 KB)
constexpr size_t WS_N      = WS_E2 + sizeof(float) * (size_t)KC;           // float[1]
constexpr size_t WS_LOSSD  = alignup(WS_N + sizeof(float), 8);             // double[1]
constexpr size_t WS_EMBPK  = alignup(WS_LOSSD + 8, 64);                    // 256*4096 packed emb

__device__ __forceinline__ void gload16(const void* g, void* l) {
    __builtin_amdgcn_global_load_lds(
        (const __attribute__((address_space(1))) unsigned int*)g,
        (__attribute__((address_space(3))) unsigned int*)l, 16, 0, 0);
}

// ---------------- kernel: pack emb -> 4KB group blocks + e2s table + zero counts ----
// group g at g*4096: frag f (0:hi-h0,1:hi-h1,2:lo-h0,3:lo-h1) at f*1024, lane l at
// +l*16 holds e[g*16+(l&15)][h*32 + (l>>4)*8 .. +8].  e2s[k] = 2^11*0.5*||e_k||^2.
__global__ void k_prep(const float* __restrict__ emb, char* __restrict__ emb_pk,
                       float* __restrict__ e2s, int* __restrict__ counts) {
    if (threadIdx.x < 32) counts[blockIdx.x * 32 + threadIdx.x] = 0;
    int t = blockIdx.x * 256 + threadIdx.x;   // 0 .. 32767
    int c = t >> 3, q = t & 7;                // code, d-chunk of 8
    const float* ep = emb + (size_t)c * DIM + q * 8;
    f16x8 hv, lv;
    float s = 0.f;
    #pragma unroll
    for (int e = 0; e < 8; ++e) {
        float x = ep[e];
        _Float16 h = (_Float16)x;
        float r = x - (float)h;
        hv[e] = h;                          // raw e_hi
        lv[e] = (_Float16)(r * 2048.0f);    // 2^11 * e_lo
        s = fmaf(x, x, s);
    }
    s += __shfl_xor(s, 1, 64);
    s += __shfl_xor(s, 2, 64);
    s += __shfl_xor(s, 4, 64);
    if (q == 0) e2s[c] = 1024.0f * s;       // 2^11 * (0.5 * sum e^2)
    int g = c >> 4, lc = c & 15;
    int h = q >> 2, lq = q & 3;
    int lane = lq * 16 + lc;
    char* base = emb_pk + (size_t)g * RB + lane * 16;
    *(f16x8*)(base + h * 1024)       = hv;
    *(f16x8*)(base + (2 + h) * 1024) = lv;
}

// ---------------- kernel: MFMA distance argmin, LDS-ring staged (T3/T4) ----------------
// 512 blocks x 192 threads (3 waves) = exactly 2 blocks/CU. Wave owns 48 rows
// (3 x 16-row fragments, 18 MFMAs/group). Block stages each 4KB code-group ONCE
// into a 12-slot LDS ring via global_load_lds; raw s_barrier + vmcnt(8) once per
// 4-group iteration (counted, never 0 in-loop). e2s table LDS-resident.
__global__ __launch_bounds__(192, 2) void k_argmin8(
        const float* __restrict__ z, const char* __restrict__ emb_pk,
        const float* __restrict__ e2s,
        int* __restrict__ codes_i, float* __restrict__ codes_f,
        int* __restrict__ counts) {
    __shared__ __align__(16) char lds[RING * RB + 16384];   // 48 KB ring + 16 KB e2s
    __shared__ int codebuf[3][48];
    constexpr int E2OFF = RING * RB;

    const int tid = threadIdx.x;
    const int l   = tid & 63;
    const int w   = tid >> 6;
    const int lc  = l & 15;
    const int lq  = l >> 4;
    const int waveRow = blockIdx.x * 144 + w * 48;

    // ---- A fragments: 48 z-rows -> three negated scaled fp16 forms ----
    f16x8 ah2k[3][2], ahr[3][2], al2k[3][2];
    #pragma unroll
    for (int rt = 0; rt < 3; ++rt)
        #pragma unroll
        for (int h = 0; h < 2; ++h) {
            const float* zp = z + (size_t)(waveRow + rt * 16 + lc) * DIM + h * 32 + lq * 8;
            float4 x0 = *(const float4*)zp;
            float4 x1 = *(const float4*)(zp + 4);
            float xs[8] = {x0.x, x0.y, x0.z, x0.w, x1.x, x1.y, x1.z, x1.w};
            #pragma unroll
            for (int e = 0; e < 8; ++e) {
                _Float16 hh = (_Float16)xs[e];
                float rr = xs[e] - (float)hh;
                ahr[rt][h][e]  = -hh;
                ah2k[rt][h][e] = (_Float16)(-2048.0f * (float)hh);   // exact pow2 scale
                al2k[rt][h][e] = -(_Float16)(rr * 2048.0f);
            }
        }

    float best[3][4];
    int   bestg[3][4];
    #pragma unroll
    for (int rt = 0; rt < 3; ++rt)
        #pragma unroll
        for (int j = 0; j < 4; ++j) { best[rt][j] = INFINITY; bestg[rt][j] = 0; }

    // ---- stage group GS (clamped dummy past 255) into ring slot GS%RING ----
    // wave w stages slice w; ALL waves stage slice 3 (identical bytes, benign) ->
    // uniform 2 gload_lds issues per wave per group.
#define STAGE(GS) {                                                         \
        int slot_ = (GS) % RING;                                            \
        int gsrc_ = (GS) < 256 ? (GS) : 255;                                \
        const char* gp_ = emb_pk + (size_t)gsrc_ * RB + (l << 4);           \
        char* lp_ = lds + slot_ * RB;                                       \
        gload16(gp_ + w * 1024, lp_ + w * 1024);                            \
        gload16(gp_ + 3072,     lp_ + 3072); }

#define LOADL(EV, B0, B1, B2, B3, G) {                                      \
        const char* p_ = lds + ((G) % RING) * RB + (l << 4);                \
        B0 = *(const f16x8*)(p_);                                           \
        B1 = *(const f16x8*)(p_ + 1024);                                    \
        B2 = *(const f16x8*)(p_ + 2048);                                    \
        B3 = *(const f16x8*)(p_ + 3072);                                    \
        EV = *(const float*)(lds + E2OFF + (((G) * 16 + lc) << 2)); }

#define COMP(B0, B1, B2, B3, EV, G) {                                             \
        f32x4 ci; ci[0] = EV; ci[1] = EV; ci[2] = EV; ci[3] = EV;                 \
        _Pragma("unroll")                                                         \
        for (int rt = 0; rt < 3; ++rt) {                                          \
            f32x4 acc = __builtin_amdgcn_mfma_f32_16x16x32_f16(ah2k[rt][0], B0, ci, 0, 0, 0); \
            acc = __builtin_amdgcn_mfma_f32_16x16x32_f16(ah2k[rt][1], B1, acc, 0, 0, 0);      \
            acc = __builtin_amdgcn_mfma_f32_16x16x32_f16(ahr[rt][0],  B2, acc, 0, 0, 0);      \
            acc = __builtin_amdgcn_mfma_f32_16x16x32_f16(ahr[rt][1],  B3, acc, 0, 0, 0);      \
            acc = __builtin_amdgcn_mfma_f32_16x16x32_f16(al2k[rt][0], B0, acc, 0, 0, 0);      \
            acc = __builtin_amdgcn_mfma_f32_16x16x32_f16(al2k[rt][1], B1, acc, 0, 0, 0);      \
            _Pragma("unroll")                                                     \
            for (int j = 0; j < 4; ++j) {                                         \
                if (acc[j] < best[rt][j]) { best[rt][j] = acc[j]; bestg[rt][j] = (G); } \
            }                                                                     \
        } }

    // ---- prologue: e2s table (16 KB, slices round-robin) + first 8 groups ----
    for (int s = w; s < 16; s += 3)
        gload16((const char*)e2s + s * 1024 + (l << 4), lds + E2OFF + s * 1024);
    for (int gs = 0; gs < 8; ++gs) STAGE(gs);
    asm volatile("s_waitcnt vmcnt(16)" ::: "memory");   // e2s done (16 stage loads pending)
    __builtin_amdgcn_s_barrier();
    __builtin_amdgcn_sched_barrier(0);

    {
        f16x8 A0, A1, A2, A3, B0, B1, B2, B3;
        float eA, eB;
        for (int t = 0; t < 256; t += 4) {
            // invariant at top: 16 own loads outstanding = groups [t+4, t+12)
            asm volatile("s_waitcnt vmcnt(8)" ::: "memory");   // groups [t,t+4) staged (own)
            __builtin_amdgcn_s_barrier();                      // ... by ALL waves
            __builtin_amdgcn_sched_barrier(0);
            LOADL(eA, A0, A1, A2, A3, t);
            LOADL(eB, B0, B1, B2, B3, t + 1);
            COMP(A0, A1, A2, A3, eA, t);
            LOADL(eA, A0, A1, A2, A3, t + 2);
            COMP(B0, B1, B2, B3, eB, t + 1);
            LOADL(eB, B0, B1, B2, B3, t + 3);
            COMP(A0, A1, A2, A3, eA, t + 2);
            COMP(B0, B1, B2, B3, eB, t + 3);
            // refill: groups [t+8, t+12) -> slots == (t-4..t-1)%RING, read in iter t-4,
            // all waves past that (barrier above) -> safe to overwrite.
            STAGE(t + 8) STAGE(t + 9) STAGE(t + 10) STAGE(t + 11)
        }
    }
    asm volatile("s_waitcnt vmcnt(0)" ::: "memory");   // drain dummy tail stages
    __builtin_amdgcn_sched_barrier(0);
#undef STAGE
#undef LOADL
#undef COMP

    // ---- butterfly argmin reduce over the 16 lanes of each lq-group ----
    #pragma unroll
    for (int rt = 0; rt < 3; ++rt)
        #pragma unroll
        for (int j = 0; j < 4; ++j) {
            float b = best[rt][j];
            int   k = bestg[rt][j] * 16 + lc;
            #pragma unroll
            for (int m = 1; m < 16; m <<= 1) {
                float obv = __shfl_xor(b, m, 64);
                int   okv = __shfl_xor(k, m, 64);
                if (obv < b || (obv == b && okv < k)) { b = obv; k = okv; }
            }
            if (lc == 0) codebuf[w][rt * 16 + lq * 4 + j] = k;   // D row = lq*4+j
        }

    // ---- emit codes + int counts (within-wave LDS dep only; no barrier) ----
    if (l < 48) {
        int code = codebuf[w][l];
        size_t rowg = (size_t)waveRow + l;
        codes_i[rowg] = code;
        codes_f[rowg] = (float)code;
        atomicAdd(&counts[code], 1);
    }
}

// ---------------- kernel: scan counts -> offsets/cursor + cluster-size + n + loss=0 ----
__global__ void k_scan(const int* __restrict__ counts,
                       int* __restrict__ offsets, int* __restrict__ cursor,
                       const float* __restrict__ ema_cs, float* __restrict__ ncs_out,
                       float* __restrict__ n_out, double* __restrict__ lossp) {
    __shared__ int   part[256];
    __shared__ float fpart[256];
    int tid = threadIdx.x;
    if (tid == 0) *lossp = 0.0;
    int base = tid * 16;
    int loc[16];
    int s = 0;
    float fs = 0.f;
    #pragma unroll
    for (int j = 0; j < 16; ++j) {
        int cnt = counts[base + j];
        loc[j] = s; s += cnt;
        float v = 0.99f * ema_cs[base + j] + 0.01f * (float)cnt;
        ncs_out[base + j] = v;
        fs += v;
    }
    part[tid] = s;
    fpart[tid] = fs;
    __syncthreads();
    for (int off = 1; off < 256; off <<= 1) {
        int v = (tid >= off) ? part[tid - off] : 0;
        __syncthreads();
        part[tid] += v;
        __syncthreads();
    }
    int excl = part[tid] - s;
    #pragma unroll
    for (int j = 0; j < 16; ++j) {
        int o = excl + loc[j];
        offsets[base + j] = o;
        cursor[base + j]  = o;
    }
    if (tid == 255) offsets[KC] = excl + s;
    for (int m = 128; m > 0; m >>= 1) {
        if (tid < m) fpart[tid] += fpart[tid + m];
        __syncthreads();
    }
    if (tid == 0) n_out[0] = fpart[0];
}

// ---------------- kernel: scatter row indices into code-sorted order ----------------
__global__ void k_scatteridx(const int* __restrict__ codes_i,
                             int* __restrict__ cursor, int* __restrict__ sorted_rows) {
    int r = blockIdx.x * 256 + threadIdx.x;
    if (r < NROWS) {
        int c = codes_i[r];
        int p = atomicAdd(&cursor[c], 1);
        sorted_rows[p] = r;
    }
}

// ---------------- kernel: segmented sum -> dw, fused EMA-w + new embedding ----------------
__global__ __launch_bounds__(64) void k_dwsum(
        const float* __restrict__ z, const int* __restrict__ offsets,
        const int* __restrict__ sorted_rows, const float* __restrict__ ema_w,
        const float* __restrict__ ncs, const float* __restrict__ nptr,
        float* __restrict__ new_ema_w_out, float* __restrict__ new_emb_out) {
    int k = blockIdx.x, tid = threadIdx.x;
    int beg = offsets[k], end = offsets[k + 1];
    float a0 = 0.f, a1 = 0.f, a2 = 0.f, a3 = 0.f;
    int i = beg;
    for (; i + 3 < end; i += 4) {
        int r0 = sorted_rows[i], r1 = sorted_rows[i + 1];
        int r2 = sorted_rows[i + 2], r3 = sorted_rows[i + 3];
        a0 += z[(size_t)r0 * DIM + tid];
        a1 += z[(size_t)r1 * DIM + tid];
        a2 += z[(size_t)r2 * DIM + tid];
        a3 += z[(size_t)r3 * DIM + tid];
    }
    for (; i < end; ++i) a0 += z[(size_t)sorted_rows[i] * DIM + tid];
    float dwv = (a0 + a1) + (a2 + a3);
    size_t idx = (size_t)k * DIM + tid;
    float n = nptr[0];
    float nw = 0.99f * ema_w[idx] + 0.01f * dwv;
    float cs = (ncs[k] + 1e-5f) / (n + 4096.0f * 1e-5f) * n;
    new_ema_w_out[idx] = nw;
    new_emb_out[idx] = nw / cs;
}

// ---------------- kernel: quantize + straight-through + loss ----------------
__global__ __launch_bounds__(256) void k_quant(
        const float* __restrict__ z, const float* __restrict__ new_emb,
        const int* __restrict__ codes, float* __restrict__ zq_out,
        double* __restrict__ loss_acc) {
    __shared__ double red[256];
    const int nvec = NELEM / 4;
    int t = blockIdx.x * 256 + threadIdx.x;
    int stride = gridDim.x * 256;
    double ls = 0.0;
    for (int v = t; v < nvec; v += stride) {
        int e0 = v * 4;
        int n  = e0 >> 6;
        int d0 = e0 & 63;
        int code = codes[n];
        float4 zq = *(const float4*)&new_emb[(size_t)code * DIM + d0];
        float4 zv = *(const float4*)&z[e0];
        float dx = zq.x - zv.x, dy = zq.y - zv.y, dz = zq.z - zv.z, dw4 = zq.w - zv.w;
        float4 o;
        o.x = zv.x + dx; o.y = zv.y + dy; o.z = zv.z + dz; o.w = zv.w + dw4;
        *(float4*)&zq_out[e0] = o;
        ls += (double)(dx * dx) + (double)(dy * dy) + (double)(dz * dz) + (double)(dw4 * dw4);
    }
    red[threadIdx.x] = ls;
    __syncthreads();
    for (int m = 128; m > 0; m >>= 1) {
        if (threadIdx.x < m) red[threadIdx.x] += red[threadIdx.x + m];
        __syncthreads();
    }
    if (threadIdx.x == 0) atomicAdd(loss_acc, red[0]);
}

__global__ void k_loss(const double* __restrict__ loss_acc, float* __restrict__ out0) {
    out0[0] = (float)(0.25 * (loss_acc[0] / (double)NELEM));
}

// ---------------- launcher ----------------
extern "C" void kernel_launch(void* const* d_in, const int* in_sizes, int n_in,
                              void* d_out, int out_size, void* d_ws, size_t ws_size,
                              hipStream_t stream) {
    const float* z      = (const float*)d_in[0];
    const float* emb    = (const float*)d_in[1];
    const float* ema_cs = (const float*)d_in[2];
    const float* ema_w  = (const float*)d_in[3];
    float* out = (float*)d_out;
    char*  ws  = (char*)d_ws;

    int*    codes_i = (int*)(ws + WS_CODES);
    int*    counts  = (int*)(ws + WS_COUNTS);
    int*    offsets = (int*)(ws + WS_OFFS);
    int*    cursor  = (int*)(ws + WS_CURSOR);
    int*    sorted  = (int*)(ws + WS_SORTED);
    float*  e2s     = (float*)(ws + WS_E2);
    float*  nptr    = (float*)(ws + WS_N);
    double* lossp   = (double*)(ws + WS_LOSSD);
    char*   emb_pk  = ws + WS_EMBPK;

    k_prep<<<(KC * 8) / 256, 256, 0, stream>>>(emb, emb_pk, e2s, counts);
    k_argmin8<<<NROWS / 144, 192, 0, stream>>>(z, emb_pk, e2s, codes_i,
                                               out + OUT_CODES, counts);
    k_scan<<<1, 256, 0, stream>>>(counts, offsets, cursor, ema_cs,
                                  out + OUT_NCS, nptr, lossp);
    k_scatteridx<<<(NROWS + 255) / 256, 256, 0, stream>>>(codes_i, cursor, sorted);
    k_dwsum<<<KC, 64, 0, stream>>>(z, offsets, sorted, ema_w,
                                   out + OUT_NCS, nptr, out + OUT_NEW, out + OUT_EMB);
    k_quant<<<1152, 256, 0, stream>>>(z, out + OUT_EMB, codes_i,
                                      out + OUT_ZQ, lossp);
    k_loss<<<1, 1, 0, stream>>>(lossp, out + OUT_LOSS);
}